// Round 11
// baseline (156.449 us; speedup 1.0000x reference)
//
#include <hip/hip_runtime.h>

#define N_NODES 100000
#define N_EDGES 640000
#define F 128
#define NT32 3125        // 32-node tiles (100000 = 3125*32 exactly)
#define NPB 256          // node_proj blocks (1/CU); tiles stride NPB

typedef __attribute__((ext_vector_type(8))) short short8;
typedef __attribute__((ext_vector_type(4))) float float4v;

// RNE float -> bf16 bits
static __device__ __forceinline__ unsigned short f2bf(float f) {
    unsigned int u = __float_as_uint(f);
    u += 0x7fffu + ((u >> 16) & 1u);
    return (unsigned short)(u >> 16);
}

// ---------------------------------------------------------------------------
// Kernel 0: transpose+convert W1 (fp32 [256][128]) into Wt bf16 [256][128]:
//   Wt[n][k] = W1[(n&128)+k][n&127]
// ---------------------------------------------------------------------------
__global__ __launch_bounds__(256) void prep_wt(
    const float* __restrict__ W1, unsigned short* __restrict__ Wt)
{
    int id = blockIdx.x * 256 + threadIdx.x;       // 0 .. 32767
    int n = id >> 7, k = id & 127;
    float v = W1[((n & 128) + k) * 128 + (n & 127)];
    Wt[id] = f2bf(v);
}

// ---------------------------------------------------------------------------
// Kernel 1: node projections — ONE barrier per tile (r10 had 2; the
// vmcnt(0)-before-s_barrier drain serialized stores/loads: ~5900 cyc/iter
// vs ~1300 of work). 512 thr (8 waves), 1 block/CU, 32-node tiles.
// Everything double-buffered; epilogue pipelined one tile back.
//   iter k (tile t): LOADH(t+1)->regs | STORES(t-1) from oX[pb^1] |
//     MFMA(t) from hb[cur] | CVT(t+1)->hb[cur^1] | OSTAGE(t)->oX[pb] | B
//   Hazard audit (all separated by >=1 barrier):
//     CVT(k)->hb[k+1 mod 2]: last read MFMA(k-1) pre-B(k-1); next read
//       MFMA(k+1) post-B(k).  OSTAGE(k)->oX[k mod 2]: read by STORES in
//       iter k+1 (post-B(k)); next write iter k+2 post-B(k+1).
//   Wave w owns output cols [w*32,(w+1)*32) of (A|B): w<4 -> A (+b1).
//   Wt in XOR-swizzled LDS chunks (r10-verified): slot r*16 + (c^(r&15)).
// LDS: 64 (Wt) + 2x8.5 (hb, stride 136) + 4x8.25 (oA/oB, stride 132)
//    = 114 KB -> 1 block/CU, 8 waves.
// ---------------------------------------------------------------------------
__global__ __launch_bounds__(512, 1) void node_proj(
    const float* __restrict__ h, const unsigned short* __restrict__ Wt,
    const float* __restrict__ b1,
    unsigned short* __restrict__ A, unsigned short* __restrict__ B)
{
    __shared__ unsigned short w_swz[256 * 128];    // 64 KB, swizzled chunks
    __shared__ unsigned short hb[2][32 * 136];     // 2 x 8.5 KB
    __shared__ unsigned short oA[2][32 * 132];     // 2 x 8.25 KB
    __shared__ unsigned short oB[2][32 * 132];     // 2 x 8.25 KB

    const int tid  = threadIdx.x;
    const int lane = tid & 63;
    const int l16  = lane & 15;
    const int quad = lane >> 4;
    const int w    = tid >> 6;            // wave id 0..7

    // ---- stage full Wt into swizzled LDS (coalesced) ----
#pragma unroll
    for (int i = 0; i < 8; ++i) {
        int cl = i * 512 + tid;           // chunk id 0..4095
        int r = cl >> 4, c = cl & 15;
        uint4 v = *(const uint4*)(Wt + (size_t)r * F + c * 8);
        *(uint4*)&w_swz[((r << 4) + (c ^ (r & 15))) * 8] = v;
    }

    const bool isA = (w < 4);
    const int colb = (w & 3) * 32;        // col base within the 128-wide half
    float4 bv[2];
#pragma unroll
    for (int p = 0; p < 2; ++p) {
        int col = colb + p * 16 + quad * 4;
        bv[p] = isA ? *(const float4*)(b1 + col) : make_float4(0.f, 0.f, 0.f, 0.f);
    }

    // staging coords: float4 f = i*512+tid, i<2; row=f>>5 (0..31), c4=f&31
    int srow[2], sc4[2];
#pragma unroll
    for (int i = 0; i < 2; ++i) { int f = i * 512 + tid; srow[i] = f >> 5; sc4[i] = f & 31; }

#define LOADH(PF, T)                                                           \
    _Pragma("unroll") for (int i = 0; i < 2; ++i)                              \
        PF[i] = *(const float4*)(h + ((size_t)(T) * 32 + srow[i]) * F + sc4[i] * 4);

#define CVTWRITE(PF, DST)                                                      \
    _Pragma("unroll") for (int i = 0; i < 2; ++i) {                            \
        uint2 p;                                                               \
        p.x = (unsigned)f2bf(PF[i].x) | ((unsigned)f2bf(PF[i].y) << 16);       \
        p.y = (unsigned)f2bf(PF[i].z) | ((unsigned)f2bf(PF[i].w) << 16);       \
        *(uint2*)&(DST)[srow[i] * 136 + sc4[i] * 4] = p;                       \
    }

    // store-phase coords: 512 thr cover 32 rows x 16 chunks
    const int strow = tid >> 4, stc = tid & 15;

    int t = blockIdx.x;                   // 256 <= 3125: tile 0 always valid
    float4 pf[2];
    LOADH(pf, t); CVTWRITE(pf, hb[0]);
    __syncthreads();                      // Wt + tile 0 staged

    int cur = 0, pb = 0, tprev = -1;
    while (t < NT32) {
        const int tn = t + NPB;
        const bool actn = (tn < NT32);
        if (actn) LOADH(pf, tn);          // prefetch next tile into regs

        // ---- stores of tile t-1 (oX[pb^1] synced by last barrier);
        //      issued early -> full MFMA phase of vmcnt drain cover ----
        if (tprev >= 0) {
            const size_t goff = ((size_t)tprev * 32 + strow) * F + stc * 8;
            *(uint4*)(A + goff) = *(const uint4*)&oA[pb ^ 1][strow * 132 + stc * 8];
            *(uint4*)(B + goff) = *(const uint4*)&oB[pb ^ 1][strow * 132 + stc * 8];
        }

        // ---- MFMA tile t: wave w -> 2 wtiles x 2 ntiles ----
        float4v acc[2][2];
#pragma unroll
        for (int p = 0; p < 2; ++p)
#pragma unroll
            for (int nt = 0; nt < 2; ++nt) acc[p][nt] = (float4v){0.f, 0.f, 0.f, 0.f};
#pragma unroll
        for (int k0 = 0; k0 < 4; ++k0) {
            const int kb = k0 * 32 + quad * 8;
            short8 bf[2];
#pragma unroll
            for (int nt = 0; nt < 2; ++nt)
                bf[nt] = *(const short8*)&hb[cur][(nt * 16 + l16) * 136 + kb];
            const int cc = k0 * 4 + quad;
#pragma unroll
            for (int p = 0; p < 2; ++p) {
                const int row = w * 32 + p * 16 + l16;     // row & 15 == l16
                short8 af = *(const short8*)&w_swz[((row << 4) + (cc ^ l16)) * 8];
#pragma unroll
                for (int nt = 0; nt < 2; ++nt)
                    acc[p][nt] = __builtin_amdgcn_mfma_f32_16x16x32_bf16(
                        af, bf[nt], acc[p][nt], 0, 0, 0);
            }
        }

        // ---- stage next h tile (hb[cur^1]: last read pre-previous barrier) ----
        if (actn) CVTWRITE(pf, hb[cur ^ 1]);

        // ---- stage outputs into oX[pb] (read next iter post-barrier) ----
        {
            unsigned short* ost = (isA ? oA : oB)[pb];
#pragma unroll
            for (int p = 0; p < 2; ++p)
#pragma unroll
                for (int nt = 0; nt < 2; ++nt) {
                    ushort4 sv;
                    sv.x = f2bf(acc[p][nt][0] + bv[p].x);
                    sv.y = f2bf(acc[p][nt][1] + bv[p].y);
                    sv.z = f2bf(acc[p][nt][2] + bv[p].z);
                    sv.w = f2bf(acc[p][nt][3] + bv[p].w);
                    *(ushort4*)&ost[(nt * 16 + l16) * 132 + colb + p * 16 + quad * 4] = sv;
                }
        }
        __syncthreads();                  // the ONE barrier
        tprev = t; t = tn; cur ^= 1; pb ^= 1;
    }
    // trailing stores for the last tile (synced by final barrier)
    if (tprev >= 0) {
        const size_t goff = ((size_t)tprev * 32 + strow) * F + stc * 8;
        *(uint4*)(A + goff) = *(const uint4*)&oA[pb ^ 1][strow * 132 + stc * 8];
        *(uint4*)(B + goff) = *(const uint4*)&oB[pb ^ 1][strow * 132 + stc * 8];
    }
#undef LOADH
#undef CVTWRITE
}

// ---------------------------------------------------------------------------
// Kernel 2: per-edge score from bf16 A,B — at its structural floor (~45 us):
// r5 (4x MLP -> 0), r7 (warm cache -> 0), r10 (line-per-instr halved -> 0)
// pin it at the aggregate random-line service wall. Unchanged.
// ---------------------------------------------------------------------------
__global__ __launch_bounds__(256) void edge_score(
    const unsigned short* __restrict__ A, const unsigned short* __restrict__ B,
    const int* __restrict__ src, const int* __restrict__ dst,
    const float* __restrict__ W2, const float* __restrict__ b2,
    float* __restrict__ out)
{
    const int tid = threadIdx.x;
    const int sub = tid & 7;
    const int e0  = blockIdx.x * 128 + (tid >> 3) * 4;

    const int4 sv = *(const int4*)(src + e0);
    const int4 dv = *(const int4*)(dst + e0);
    const int s[4] = {sv.x, sv.y, sv.z, sv.w};
    const int d[4] = {dv.x, dv.y, dv.z, dv.w};

    uint4 av0[4], av1[4], bv0[4], bv1[4];
#pragma unroll
    for (int i = 0; i < 4; ++i) {
        const unsigned short* Ar = A + (size_t)s[i] * F;
        const unsigned short* Br = B + (size_t)d[i] * F;
        av0[i] = *(const uint4*)(Ar + sub * 8);
        av1[i] = *(const uint4*)(Ar + 64 + sub * 8);
        bv0[i] = *(const uint4*)(Br + sub * 8);
        bv1[i] = *(const uint4*)(Br + 64 + sub * 8);
    }

    const float4 w0 = *(const float4*)(W2 + sub * 8);
    const float4 w1 = *(const float4*)(W2 + sub * 8 + 4);
    const float4 w2 = *(const float4*)(W2 + 64 + sub * 8);
    const float4 w3 = *(const float4*)(W2 + 64 + sub * 8 + 4);
    const float bias = b2[0];

#define TERM(UA, UB, WL, WH)                                                   \
    {                                                                          \
        float fa0 = __uint_as_float((UA) << 16);                               \
        float fa1 = __uint_as_float((UA) & 0xFFFF0000u);                       \
        float fb0 = __uint_as_float((UB) << 16);                               \
        float fb1 = __uint_as_float((UB) & 0xFFFF0000u);                       \
        sacc = fmaf(fmaxf(fa0 + fb0, 0.f), (WL), sacc);                        \
        sacc = fmaf(fmaxf(fa1 + fb1, 0.f), (WH), sacc);                        \
    }
#pragma unroll
    for (int i = 0; i < 4; ++i) {
        float sacc = 0.f;
        TERM(av0[i].x, bv0[i].x, w0.x, w0.y)
        TERM(av0[i].y, bv0[i].y, w0.z, w0.w)
        TERM(av0[i].z, bv0[i].z, w1.x, w1.y)
        TERM(av0[i].w, bv0[i].w, w1.z, w1.w)
        TERM(av1[i].x, bv1[i].x, w2.x, w2.y)
        TERM(av1[i].y, bv1[i].y, w2.z, w2.w)
        TERM(av1[i].z, bv1[i].z, w3.x, w3.y)
        TERM(av1[i].w, bv1[i].w, w3.z, w3.w)
        sacc += __shfl_xor(sacc, 1);
        sacc += __shfl_xor(sacc, 2);
        sacc += __shfl_xor(sacc, 4);
        if (sub == 0) out[e0 + i] = sacc + bias;
    }
#undef TERM
}

extern "C" void kernel_launch(void* const* d_in, const int* in_sizes, int n_in,
                              void* d_out, int out_size, void* d_ws, size_t ws_size,
                              hipStream_t stream) {
    const float* h   = (const float*)d_in[0];
    const int*   src = (const int*)d_in[1];
    const int*   dst = (const int*)d_in[2];
    const float* W1  = (const float*)d_in[3];
    const float* b1  = (const float*)d_in[4];
    const float* W2  = (const float*)d_in[5];
    const float* b2  = (const float*)d_in[6];
    float* out = (float*)d_out;

    // workspace layout (bf16): Wt[256][128] | A[100000][128] | B[100000][128]
    unsigned short* Wt = (unsigned short*)d_ws;
    unsigned short* A  = Wt + 256 * 128;
    unsigned short* B  = A + (size_t)N_NODES * F;

    prep_wt<<<128, 256, 0, stream>>>(W1, Wt);
    node_proj<<<NPB, 512, 0, stream>>>(h, Wt, b1, A, B);
    edge_score<<<N_EDGES / 128, 256, 0, stream>>>(A, B, src, dst, W2, b2, out);
}